// Round 5
// baseline (1446.912 us; speedup 1.0000x reference)
//
#include <hip/hip_runtime.h>
#include <hip/hip_bf16.h>
#include <cstdint>
#include <cstddef>

// Problem constants
#define E_TOT   1048576
#define BGR     64
#define NN      1024
#define DD      128
#define HID     256
#define NH      4
#define NSEG    65536
#define KDIM    96           // x in bf16; ctxt (globs/cndts) folded separately
#define NKCH    12           // KDIM/8 chunks
#define MLP_BLOCKS 1024      // 4 waves each -> 4096 waves
#define GRP_PER_WAVE 8       // 8 groups x 32 edges = 256 edges per wave

typedef __attribute__((ext_vector_type(8))) short s16x8;   // 8 bf16
typedef __attribute__((ext_vector_type(4))) float f32x4;

static __device__ __forceinline__ unsigned short f2bf_rn(float f) {
    unsigned u = __float_as_uint(f);
    unsigned r = u + 0x7FFF + ((u >> 16) & 1);   // round-to-nearest-even
    return (unsigned short)(r >> 16);
}

// ---------------------------------------------------------------------------
// Prep A: Wg [12 kchunk][256 hidden][8] bf16 = bf16(W1[0:96])  (MFMA A layout)
// ---------------------------------------------------------------------------
__global__ __launch_bounds__(256)
void k_prep_w(const float* __restrict__ W1, short* __restrict__ Wg) {
    int idx = blockIdx.x * 256 + threadIdx.x;        // < 12*256*8 = 24576
    int kchunk = idx >> 11;
    int n      = (idx >> 3) & 255;
    int j      = idx & 7;
    int k      = kchunk * 8 + j;                     // 0..95
    Wg[idx] = (short)f2bf_rn(W1[k * 256 + n]);
}

// ---------------------------------------------------------------------------
// Prep B: ctxtc[64][256] = b1 + globs[b]·W1[96:104] + cndts[b]·W1[104:112]
// ---------------------------------------------------------------------------
__global__ __launch_bounds__(256)
void k_prep_ctx(const float* __restrict__ W1, const float* __restrict__ b1,
                const float* __restrict__ globs, const float* __restrict__ cndts,
                float* __restrict__ ctxtc) {
    int b = blockIdx.x, j = threadIdx.x;
    float s = b1[j];
    #pragma unroll
    for (int g = 0; g < 8; ++g) s = fmaf(globs[b * 8 + g], W1[(96 + g) * 256 + j], s);
    #pragma unroll
    for (int c = 0; c < 8; ++c) s = fmaf(cndts[b * 8 + c], W1[(104 + c) * 256 + j], s);
    ctxtc[b * 256 + j] = s;
}

// ---------------------------------------------------------------------------
// Count edges per segment
// ---------------------------------------------------------------------------
__global__ __launch_bounds__(256)
void k_count(const int* __restrict__ batch_idx, const int* __restrict__ recv_idx,
             int* __restrict__ counts)
{
    int e = blockIdx.x * 256 + threadIdx.x;
    atomicAdd(&counts[batch_idx[e] * NN + recv_idx[e]], 1);
}

// ---------------------------------------------------------------------------
// Parallel exclusive scan of counts[65536]: 3 small kernels
// ---------------------------------------------------------------------------
__global__ __launch_bounds__(256)
void k_scan1(const int* __restrict__ counts, int* __restrict__ tmp_excl,
             int* __restrict__ blocksums)
{
    __shared__ int sh[256];
    const int t = threadIdx.x;
    const int gid = blockIdx.x * 256 + t;
    int c = counts[gid];
    sh[t] = c;
    __syncthreads();
    int v = c;
    for (int off = 1; off < 256; off <<= 1) {
        int u = (t >= off) ? sh[t - off] : 0;
        __syncthreads();
        v += u; sh[t] = v;
        __syncthreads();
    }
    tmp_excl[gid] = v - c;
    if (t == 255) blocksums[blockIdx.x] = v;
}

__global__ __launch_bounds__(256)
void k_scan2(int* __restrict__ blocksums)
{
    __shared__ int sh[256];
    const int t = threadIdx.x;
    int c = blocksums[t];
    sh[t] = c;
    __syncthreads();
    int v = c;
    for (int off = 1; off < 256; off <<= 1) {
        int u = (t >= off) ? sh[t - off] : 0;
        __syncthreads();
        v += u; sh[t] = v;
        __syncthreads();
    }
    blocksums[t] = v - c;
}

__global__ __launch_bounds__(256)
void k_scan3(const int* __restrict__ tmp_excl, const int* __restrict__ blocksums,
             int* __restrict__ offsets, int* __restrict__ cursor)
{
    const int gid = blockIdx.x * 256 + threadIdx.x;
    int v = tmp_excl[gid] + blocksums[blockIdx.x];
    offsets[gid] = v;
    cursor[gid]  = v;
}

// ---------------------------------------------------------------------------
// Scatter edge ids into per-segment lists (counting sort)
// ---------------------------------------------------------------------------
__global__ __launch_bounds__(256)
void k_scatter(const int* __restrict__ batch_idx, const int* __restrict__ recv_idx,
               int* __restrict__ cursor, int* __restrict__ elist)
{
    int e   = blockIdx.x * 256 + threadIdx.x;
    int seg = batch_idx[e] * NN + recv_idx[e];
    int pos = atomicAdd(&cursor[seg], 1);
    elist[pos] = e;
}

// ---------------------------------------------------------------------------
// Main fused MFMA kernel (K=96 bf16), barrier-free main loop.
// 1024 blocks x 256 threads (4 waves). Each wave independently processes
// 8 groups of 32 edges: X loaded DIRECT from global (each X byte consumed by
// exactly one wave -> no LDS staging, no barriers). W (48KB, read-only) + W2
// staged once in LDS. Wave owns 32 edges x all 256 hidden: each wf LDS read
// feeds 2 MFMAs; layer-2 logit completes in-wave via 2 shfl_xor.
// ---------------------------------------------------------------------------
__global__ __launch_bounds__(256, 2)
void k_mlp_mfma(const float* __restrict__ pooled, const float* __restrict__ edges,
                const short* __restrict__ Wg,     const float* __restrict__ ctxtc,
                const float* __restrict__ W2,
                const int* __restrict__ batch_idx, const int* __restrict__ recv_idx,
                float* __restrict__ ex_out, float* __restrict__ denom)
{
    __shared__ short Wl[NKCH * 256 * 8];        // 49152 B [kchunk][hidden][8]
    __shared__ float sW2[256 * 4];              //  4096 B

    const int tid  = threadIdx.x;
    const int lane = tid & 63;
    const int wid  = tid >> 6;          // wave 0..3
    const int la   = lane & 15;
    const int g    = lane >> 4;         // 0..3 (k-chunk select / acc row group)

    // ---- prologue: W (layout prebuilt) + W2 into LDS, single barrier ----
    {
        const float4* src = reinterpret_cast<const float4*>(Wg);
        float4* dst = reinterpret_cast<float4*>(Wl);
        #pragma unroll
        for (int i = 0; i < 12; ++i) dst[i * 256 + tid] = src[i * 256 + tid];
        *reinterpret_cast<float4*>(&sW2[tid * 4]) =
            reinterpret_cast<const float4*>(W2)[tid];
    }
    __syncthreads();

    const int wglob = blockIdx.x * 4 + wid;

    for (int grp = 0; grp < GRP_PER_WAVE; ++grp) {
        const int e0 = wglob * (GRP_PER_WAVE * 32) + grp * 32;
        const int ea = e0 + la;          // ef0 edge
        const int eb = e0 + 16 + la;     // ef1 edge

        // ---- issue all X loads for the group up-front (12 float4/lane) ----
        float4 xv[3][2][2];
        #pragma unroll
        for (int ks = 0; ks < 3; ++ks) {
            #pragma unroll
            for (int ef = 0; ef < 2; ++ef) {
                const int e = e0 + ef * 16 + la;
                const float* p = (ks == 0)
                    ? (pooled + (size_t)e * 32 + g * 8)
                    : (edges + (size_t)e * 64 + (ks - 1) * 32 + g * 8);
                xv[ks][ef][0] = reinterpret_cast<const float4*>(p)[0];
                xv[ks][ef][1] = reinterpret_cast<const float4*>(p)[1];
            }
        }
        const int ba = batch_idx[ea];
        const int bb = batch_idx[eb];
        const int ra = recv_idx[ea];
        const int rb = recv_idx[eb];

        // ---- K-loop: 3 ks x (16 hf x 2 ef) MFMA; wf read once per 2 MFMAs ----
        f32x4 acc[16][2];
        #pragma unroll
        for (int i = 0; i < 16; ++i) {
            acc[i][0] = (f32x4){0.f, 0.f, 0.f, 0.f};
            acc[i][1] = (f32x4){0.f, 0.f, 0.f, 0.f};
        }

        #pragma unroll
        for (int ks = 0; ks < 3; ++ks) {
            s16x8 xf[2];
            #pragma unroll
            for (int ef = 0; ef < 2; ++ef) {
                const float vals[8] = {
                    xv[ks][ef][0].x, xv[ks][ef][0].y, xv[ks][ef][0].z, xv[ks][ef][0].w,
                    xv[ks][ef][1].x, xv[ks][ef][1].y, xv[ks][ef][1].z, xv[ks][ef][1].w };
                s16x8 hv;
                #pragma unroll
                for (int i = 0; i < 8; ++i) hv[i] = (short)f2bf_rn(vals[i]);
                xf[ef] = hv;
            }
            const short* wrow = &Wl[((ks * 4 + g) * 256 + la) * 8];
            #pragma unroll
            for (int hf = 0; hf < 16; ++hf) {
                s16x8 wf = *reinterpret_cast<const s16x8*>(wrow + hf * 128);
                acc[hf][0] = __builtin_amdgcn_mfma_f32_16x16x32_bf16(wf, xf[0], acc[hf][0], 0, 0, 0);
                acc[hf][1] = __builtin_amdgcn_mfma_f32_16x16x32_bf16(wf, xf[1], acc[hf][1], 0, 0, 0);
            }
        }

        // ---- epilogue: +ctxt, leaky, layer-2, in-wave reduce, exp, atomics ----
        const float* cxa_base = &ctxtc[(size_t)ba * 256 + g * 4];
        const float* cxb_base = &ctxtc[(size_t)bb * 256 + g * 4];
        float pa0 = 0.f, pa1 = 0.f, pa2 = 0.f, pa3 = 0.f;
        float pb0 = 0.f, pb1 = 0.f, pb2 = 0.f, pb3 = 0.f;
        #pragma unroll
        for (int hf = 0; hf < 16; ++hf) {
            const float4 cxa = *reinterpret_cast<const float4*>(cxa_base + hf * 16);
            const float4 cxb = *reinterpret_cast<const float4*>(cxb_base + hf * 16);
            const float cxaa[4] = {cxa.x, cxa.y, cxa.z, cxa.w};
            const float cxba[4] = {cxb.x, cxb.y, cxb.z, cxb.w};
            #pragma unroll
            for (int r = 0; r < 4; ++r) {
                const float4 w2v = *reinterpret_cast<const float4*>(
                    &sW2[(hf * 16 + g * 4 + r) * 4]);
                float sa = acc[hf][0][r] + cxaa[r];
                float ha = fmaxf(sa, 0.1f * sa);
                float sb = acc[hf][1][r] + cxba[r];
                float hb = fmaxf(sb, 0.1f * sb);
                pa0 = fmaf(ha, w2v.x, pa0); pb0 = fmaf(hb, w2v.x, pb0);
                pa1 = fmaf(ha, w2v.y, pa1); pb1 = fmaf(hb, w2v.y, pb1);
                pa2 = fmaf(ha, w2v.z, pa2); pb2 = fmaf(hb, w2v.z, pb2);
                pa3 = fmaf(ha, w2v.w, pa3); pb3 = fmaf(hb, w2v.w, pb3);
            }
        }
        // sum the 4 g-groups (lanes la, la+16, la+32, la+48 share an edge)
        pa0 += __shfl_xor(pa0, 16); pa0 += __shfl_xor(pa0, 32);
        pa1 += __shfl_xor(pa1, 16); pa1 += __shfl_xor(pa1, 32);
        pa2 += __shfl_xor(pa2, 16); pa2 += __shfl_xor(pa2, 32);
        pa3 += __shfl_xor(pa3, 16); pa3 += __shfl_xor(pa3, 32);
        pb0 += __shfl_xor(pb0, 16); pb0 += __shfl_xor(pb0, 32);
        pb1 += __shfl_xor(pb1, 16); pb1 += __shfl_xor(pb1, 32);
        pb2 += __shfl_xor(pb2, 16); pb2 += __shfl_xor(pb2, 32);
        pb3 += __shfl_xor(pb3, 16); pb3 += __shfl_xor(pb3, 32);
        float mla = (g == 0) ? pa0 : (g == 1) ? pa1 : (g == 2) ? pa2 : pa3;
        float mlb = (g == 0) ? pb0 : (g == 1) ? pb1 : (g == 2) ? pb2 : pb3;
        float exa = __expf(mla);             // lane g handles head g
        float exb = __expf(mlb);
        ex_out[(size_t)ea * 4 + g] = exa;
        ex_out[(size_t)eb * 4 + g] = exb;
        atomicAdd(&denom[(ba * NN + ra) * 4 + g], exa);
        atomicAdd(&denom[(bb * NN + rb) * 4 + g], exb);
    }
}

// ---------------------------------------------------------------------------
// K4: one wave per segment; lane owns 2 of 128 dims; head = lane>>4.
// 4-way unrolled so 4 independent new_edges rows are in flight.
// ---------------------------------------------------------------------------
__global__ __launch_bounds__(256)
void k_gather(const float* __restrict__ new_edges, const float* __restrict__ ex,
              const float* __restrict__ denom, const int* __restrict__ offsets,
              const int* __restrict__ counts, const int* __restrict__ elist,
              float* __restrict__ out)
{
    const int gid  = blockIdx.x * 256 + threadIdx.x;
    const int seg  = gid >> 6;
    const int lane = threadIdx.x & 63;
    if (seg >= NSEG) return;

    const int start = offsets[seg];
    const int cnt   = counts[seg];
    const int h     = lane >> 4;
    const int doff  = lane * 2;

    float a0 = 0.f, a1 = 0.f;
    int i = 0;
    for (; i + 4 <= cnt; i += 4) {
        const int el0 = elist[start + i + 0];
        const int el1 = elist[start + i + 1];
        const int el2 = elist[start + i + 2];
        const int el3 = elist[start + i + 3];
        const float w0 = ex[(size_t)el0 * 4 + h];
        const float w1 = ex[(size_t)el1 * 4 + h];
        const float w2 = ex[(size_t)el2 * 4 + h];
        const float w3 = ex[(size_t)el3 * 4 + h];
        const float2 n0 = *reinterpret_cast<const float2*>(new_edges + (size_t)el0 * DD + doff);
        const float2 n1 = *reinterpret_cast<const float2*>(new_edges + (size_t)el1 * DD + doff);
        const float2 n2 = *reinterpret_cast<const float2*>(new_edges + (size_t)el2 * DD + doff);
        const float2 n3 = *reinterpret_cast<const float2*>(new_edges + (size_t)el3 * DD + doff);
        a0 = fmaf(n0.x, w0, a0); a1 = fmaf(n0.y, w0, a1);
        a0 = fmaf(n1.x, w1, a0); a1 = fmaf(n1.y, w1, a1);
        a0 = fmaf(n2.x, w2, a0); a1 = fmaf(n2.y, w2, a1);
        a0 = fmaf(n3.x, w3, a0); a1 = fmaf(n3.y, w3, a1);
    }
    for (; i < cnt; ++i) {
        const int el = elist[start + i];
        const float w = ex[(size_t)el * 4 + h];
        const float2 n = *reinterpret_cast<const float2*>(new_edges + (size_t)el * DD + doff);
        a0 = fmaf(n.x, w, a0); a1 = fmaf(n.y, w, a1);
    }
    const float scale = (cnt > 0) ? 1.0f / denom[seg * 4 + h] : 0.0f;
    float2 r; r.x = a0 * scale; r.y = a1 * scale;
    *reinterpret_cast<float2*>(out + (size_t)seg * DD + doff) = r;
}

// ---------------------------------------------------------------------------
extern "C" void kernel_launch(void* const* d_in, const int* in_sizes, int n_in,
                              void* d_out, int out_size, void* d_ws, size_t ws_size,
                              hipStream_t stream)
{
    const float* new_edges = (const float*)d_in[0];
    const float* edges     = (const float*)d_in[1];
    const float* pooled    = (const float*)d_in[2];
    const float* globs     = (const float*)d_in[3];
    const float* cndts     = (const float*)d_in[4];
    const float* W1        = (const float*)d_in[5];
    const float* b1        = (const float*)d_in[6];
    const float* W2        = (const float*)d_in[7];
    // b2 (d_in[8]) cancels in the per-head softmax — intentionally unused
    const int*   batch_idx = (const int*)d_in[9];
    const int*   recv_idx  = (const int*)d_in[10];
    float* out = (float*)d_out;

    char* ws = (char*)d_ws;
    float* ex       = (float*)(ws);                              // 16 MB
    float* denom    = (float*)(ws + (size_t)16 * 1024 * 1024);   // 1 MB
    char*  base17   = ws + (size_t)17 * 1024 * 1024;
    int*   counts   = (int*)(base17);                            // 256 KB
    int*   offs     = (int*)(base17 + 1 * 262144);
    int*   cursor   = (int*)(base17 + 2 * 262144);
    int*   tmp_excl = (int*)(base17 + 3 * 262144);
    int*   bsums    = (int*)(base17 + 4 * 262144);               // 1 KB
    int*   elist    = (int*)(ws + (size_t)18 * 1024 * 1024);     // 4 MB
    short* Wg       = (short*)(ws + (size_t)22 * 1024 * 1024);   // 49,152 B
    float* ctxtc    = (float*)(ws + (size_t)22 * 1024 * 1024 + 65536); // 64 KB

    // denom (1 MB) + counts (256 KB) contiguous: one memset
    hipMemsetAsync(denom, 0,
                   (size_t)NSEG * NH * sizeof(float) + (size_t)NSEG * sizeof(int),
                   stream);

    // index-only chain (independent of MLP)
    k_count<<<E_TOT / 256, 256, 0, stream>>>(batch_idx, recv_idx, counts);
    k_scan1<<<NSEG / 256, 256, 0, stream>>>(counts, tmp_excl, bsums);
    k_scan2<<<1, 256, 0, stream>>>(bsums);
    k_scan3<<<NSEG / 256, 256, 0, stream>>>(tmp_excl, bsums, offs, cursor);
    k_scatter<<<E_TOT / 256, 256, 0, stream>>>(batch_idx, recv_idx, cursor, elist);

    // MLP chain
    k_prep_w<<<96, 256, 0, stream>>>(W1, Wg);
    k_prep_ctx<<<64, 256, 0, stream>>>(W1, b1, globs, cndts, ctxtc);
    k_mlp_mfma<<<MLP_BLOCKS, 256, 0, stream>>>(pooled, edges, Wg, ctxtc, W2,
                                               batch_idx, recv_idx, ex, denom);

    // final weighted pool
    k_gather<<<(NSEG * 64) / 256, 256, 0, stream>>>(new_edges, ex, denom,
                                                    offs, counts, elist, out);
}

// Round 6
// 965.041 us; speedup vs baseline: 1.4993x; 1.4993x over previous
//
#include <hip/hip_runtime.h>
#include <hip/hip_bf16.h>
#include <cstdint>
#include <cstddef>

// Problem constants
#define E_TOT   1048576
#define BGR     64
#define NN      1024
#define DD      128
#define HID     256
#define NH      4
#define NSEG    65536
#define KDIM    96           // x in bf16; ctxt (globs/cndts) folded separately
#define NKCH    12           // KDIM/8 chunks
#define MLP_BLOCKS 1024      // 4 waves each -> 4096 waves
#define GRP_PER_WAVE 8       // 8 groups x 32 edges = 256 edges per wave

typedef __attribute__((ext_vector_type(8))) short s16x8;   // 8 bf16
typedef __attribute__((ext_vector_type(4))) float f32x4;

static __device__ __forceinline__ unsigned short f2bf_rn(float f) {
    unsigned u = __float_as_uint(f);
    unsigned r = u + 0x7FFF + ((u >> 16) & 1);   // round-to-nearest-even
    return (unsigned short)(r >> 16);
}

// ---------------------------------------------------------------------------
// Prep A: Wg [12 kchunk][256 hidden][8] bf16 = bf16(W1[0:96])  (MFMA A layout)
// ---------------------------------------------------------------------------
__global__ __launch_bounds__(256)
void k_prep_w(const float* __restrict__ W1, short* __restrict__ Wg) {
    int idx = blockIdx.x * 256 + threadIdx.x;        // < 12*256*8 = 24576
    int kchunk = idx >> 11;
    int n      = (idx >> 3) & 255;
    int j      = idx & 7;
    int k      = kchunk * 8 + j;                     // 0..95
    Wg[idx] = (short)f2bf_rn(W1[k * 256 + n]);
}

// ---------------------------------------------------------------------------
// Prep B: ctxtc[64][256] = b1 + globs[b]·W1[96:104] + cndts[b]·W1[104:112]
// ---------------------------------------------------------------------------
__global__ __launch_bounds__(256)
void k_prep_ctx(const float* __restrict__ W1, const float* __restrict__ b1,
                const float* __restrict__ globs, const float* __restrict__ cndts,
                float* __restrict__ ctxtc) {
    int b = blockIdx.x, j = threadIdx.x;
    float s = b1[j];
    #pragma unroll
    for (int g = 0; g < 8; ++g) s = fmaf(globs[b * 8 + g], W1[(96 + g) * 256 + j], s);
    #pragma unroll
    for (int c = 0; c < 8; ++c) s = fmaf(cndts[b * 8 + c], W1[(104 + c) * 256 + j], s);
    ctxtc[b * 256 + j] = s;
}

// ---------------------------------------------------------------------------
// Count edges per segment
// ---------------------------------------------------------------------------
__global__ __launch_bounds__(256)
void k_count(const int* __restrict__ batch_idx, const int* __restrict__ recv_idx,
             int* __restrict__ counts)
{
    int e = blockIdx.x * 256 + threadIdx.x;
    atomicAdd(&counts[batch_idx[e] * NN + recv_idx[e]], 1);
}

// ---------------------------------------------------------------------------
// Parallel exclusive scan of counts[65536]: 3 small kernels
// ---------------------------------------------------------------------------
__global__ __launch_bounds__(256)
void k_scan1(const int* __restrict__ counts, int* __restrict__ tmp_excl,
             int* __restrict__ blocksums)
{
    __shared__ int sh[256];
    const int t = threadIdx.x;
    const int gid = blockIdx.x * 256 + t;
    int c = counts[gid];
    sh[t] = c;
    __syncthreads();
    int v = c;
    for (int off = 1; off < 256; off <<= 1) {
        int u = (t >= off) ? sh[t - off] : 0;
        __syncthreads();
        v += u; sh[t] = v;
        __syncthreads();
    }
    tmp_excl[gid] = v - c;
    if (t == 255) blocksums[blockIdx.x] = v;
}

__global__ __launch_bounds__(256)
void k_scan2(int* __restrict__ blocksums)
{
    __shared__ int sh[256];
    const int t = threadIdx.x;
    int c = blocksums[t];
    sh[t] = c;
    __syncthreads();
    int v = c;
    for (int off = 1; off < 256; off <<= 1) {
        int u = (t >= off) ? sh[t - off] : 0;
        __syncthreads();
        v += u; sh[t] = v;
        __syncthreads();
    }
    blocksums[t] = v - c;
}

__global__ __launch_bounds__(256)
void k_scan3(const int* __restrict__ tmp_excl, const int* __restrict__ blocksums,
             int* __restrict__ offsets, int* __restrict__ cursor)
{
    const int gid = blockIdx.x * 256 + threadIdx.x;
    int v = tmp_excl[gid] + blocksums[blockIdx.x];
    offsets[gid] = v;
    cursor[gid]  = v;
}

// ---------------------------------------------------------------------------
// Scatter edge ids into per-segment lists (counting sort)
// ---------------------------------------------------------------------------
__global__ __launch_bounds__(256)
void k_scatter(const int* __restrict__ batch_idx, const int* __restrict__ recv_idx,
               int* __restrict__ cursor, int* __restrict__ elist)
{
    int e   = blockIdx.x * 256 + threadIdx.x;
    int seg = batch_idx[e] * NN + recv_idx[e];
    int pos = atomicAdd(&cursor[seg], 1);
    elist[pos] = e;
}

// ---------------------------------------------------------------------------
// Main fused MFMA kernel (K=96 bf16), barrier-free main loop.
// 1024 blocks x 256 threads (4 waves). Wave owns 32 edges x 256 hidden, but
// hidden is processed in TWO halves of 128 so live acc = 8x2 f32x4 = 64 VGPR
// (round-5 lesson: acc[16][2]=128 VGPR forced scratch spill -> 3.1 GB HBM).
// X converted to bf16 fragments ONCE (xf[3][2], 24 VGPR), reused by both
// halves. Layer-2 partials carry across halves; logit finishes in-wave.
// ---------------------------------------------------------------------------
__global__ __launch_bounds__(256, 2)
void k_mlp_mfma(const float* __restrict__ pooled, const float* __restrict__ edges,
                const short* __restrict__ Wg,     const float* __restrict__ ctxtc,
                const float* __restrict__ W2,
                const int* __restrict__ batch_idx, const int* __restrict__ recv_idx,
                float* __restrict__ ex_out, float* __restrict__ denom)
{
    __shared__ short Wl[NKCH * 256 * 8];        // 49152 B [kchunk][hidden][8]
    __shared__ float sW2[256 * 4];              //  4096 B

    const int tid  = threadIdx.x;
    const int lane = tid & 63;
    const int wid  = tid >> 6;          // wave 0..3
    const int la   = lane & 15;
    const int g    = lane >> 4;         // 0..3 (k-chunk select / acc row group)

    // ---- prologue: W (layout prebuilt) + W2 into LDS, single barrier ----
    {
        const float4* src = reinterpret_cast<const float4*>(Wg);
        float4* dst = reinterpret_cast<float4*>(Wl);
        #pragma unroll
        for (int i = 0; i < 12; ++i) dst[i * 256 + tid] = src[i * 256 + tid];
        *reinterpret_cast<float4*>(&sW2[tid * 4]) =
            reinterpret_cast<const float4*>(W2)[tid];
    }
    __syncthreads();

    const int wglob = blockIdx.x * 4 + wid;

    for (int grp = 0; grp < GRP_PER_WAVE; ++grp) {
        const int e0 = wglob * (GRP_PER_WAVE * 32) + grp * 32;
        const int ea = e0 + la;          // ef0 edge
        const int eb = e0 + 16 + la;     // ef1 edge

        // ---- load X and convert to bf16 fragments immediately (frees fp32) ----
        s16x8 xf[3][2];
        #pragma unroll
        for (int ks = 0; ks < 3; ++ks) {
            #pragma unroll
            for (int ef = 0; ef < 2; ++ef) {
                const int e = e0 + ef * 16 + la;
                const float* p = (ks == 0)
                    ? (pooled + (size_t)e * 32 + g * 8)
                    : (edges + (size_t)e * 64 + (ks - 1) * 32 + g * 8);
                const float4 v0 = reinterpret_cast<const float4*>(p)[0];
                const float4 v1 = reinterpret_cast<const float4*>(p)[1];
                const float vals[8] = { v0.x, v0.y, v0.z, v0.w,
                                        v1.x, v1.y, v1.z, v1.w };
                s16x8 hv;
                #pragma unroll
                for (int i = 0; i < 8; ++i) hv[i] = (short)f2bf_rn(vals[i]);
                xf[ks][ef] = hv;
            }
        }
        const int ba = batch_idx[ea];
        const int bb = batch_idx[eb];
        const int ra = recv_idx[ea];
        const int rb = recv_idx[eb];

        float pa0 = 0.f, pa1 = 0.f, pa2 = 0.f, pa3 = 0.f;
        float pb0 = 0.f, pb1 = 0.f, pb2 = 0.f, pb3 = 0.f;

        // ---- two hidden halves of 128: acc is only 8x2 f32x4 (64 VGPR) ----
        #pragma unroll
        for (int half = 0; half < 2; ++half) {
            f32x4 acc[8][2];
            #pragma unroll
            for (int i = 0; i < 8; ++i) {
                acc[i][0] = (f32x4){0.f, 0.f, 0.f, 0.f};
                acc[i][1] = (f32x4){0.f, 0.f, 0.f, 0.f};
            }

            #pragma unroll
            for (int ks = 0; ks < 3; ++ks) {
                const short* wrow = &Wl[((ks * 4 + g) * 256 + half * 128 + la) * 8];
                #pragma unroll
                for (int hf = 0; hf < 8; ++hf) {
                    s16x8 wf = *reinterpret_cast<const s16x8*>(wrow + hf * 128);
                    acc[hf][0] = __builtin_amdgcn_mfma_f32_16x16x32_bf16(
                        wf, xf[ks][0], acc[hf][0], 0, 0, 0);
                    acc[hf][1] = __builtin_amdgcn_mfma_f32_16x16x32_bf16(
                        wf, xf[ks][1], acc[hf][1], 0, 0, 0);
                }
            }

            // ---- epilogue half: +ctxt, leaky, layer-2 partials ----
            const float* cxa_base = &ctxtc[(size_t)ba * 256 + half * 128 + g * 4];
            const float* cxb_base = &ctxtc[(size_t)bb * 256 + half * 128 + g * 4];
            #pragma unroll
            for (int hf = 0; hf < 8; ++hf) {
                const float4 cxa = *reinterpret_cast<const float4*>(cxa_base + hf * 16);
                const float4 cxb = *reinterpret_cast<const float4*>(cxb_base + hf * 16);
                const float cxaa[4] = {cxa.x, cxa.y, cxa.z, cxa.w};
                const float cxba[4] = {cxb.x, cxb.y, cxb.z, cxb.w};
                #pragma unroll
                for (int r = 0; r < 4; ++r) {
                    const int j = half * 128 + hf * 16 + g * 4 + r;
                    const float4 w2v = *reinterpret_cast<const float4*>(&sW2[j * 4]);
                    float sa = acc[hf][0][r] + cxaa[r];
                    float ha = fmaxf(sa, 0.1f * sa);     // leaky_relu(0.1)
                    float sb = acc[hf][1][r] + cxba[r];
                    float hb = fmaxf(sb, 0.1f * sb);
                    pa0 = fmaf(ha, w2v.x, pa0); pb0 = fmaf(hb, w2v.x, pb0);
                    pa1 = fmaf(ha, w2v.y, pa1); pb1 = fmaf(hb, w2v.y, pb1);
                    pa2 = fmaf(ha, w2v.z, pa2); pb2 = fmaf(hb, w2v.z, pb2);
                    pa3 = fmaf(ha, w2v.w, pa3); pb3 = fmaf(hb, w2v.w, pb3);
                }
            }
        }

        // ---- in-wave reduce (lanes la,+16,+32,+48 share an edge), exp, out ----
        pa0 += __shfl_xor(pa0, 16); pa0 += __shfl_xor(pa0, 32);
        pa1 += __shfl_xor(pa1, 16); pa1 += __shfl_xor(pa1, 32);
        pa2 += __shfl_xor(pa2, 16); pa2 += __shfl_xor(pa2, 32);
        pa3 += __shfl_xor(pa3, 16); pa3 += __shfl_xor(pa3, 32);
        pb0 += __shfl_xor(pb0, 16); pb0 += __shfl_xor(pb0, 32);
        pb1 += __shfl_xor(pb1, 16); pb1 += __shfl_xor(pb1, 32);
        pb2 += __shfl_xor(pb2, 16); pb2 += __shfl_xor(pb2, 32);
        pb3 += __shfl_xor(pb3, 16); pb3 += __shfl_xor(pb3, 32);
        float mla = (g == 0) ? pa0 : (g == 1) ? pa1 : (g == 2) ? pa2 : pa3;
        float mlb = (g == 0) ? pb0 : (g == 1) ? pb1 : (g == 2) ? pb2 : pb3;
        float exa = __expf(mla);             // lane g handles head g
        float exb = __expf(mlb);
        ex_out[(size_t)ea * 4 + g] = exa;
        ex_out[(size_t)eb * 4 + g] = exb;
        atomicAdd(&denom[(ba * NN + ra) * 4 + g], exa);
        atomicAdd(&denom[(bb * NN + rb) * 4 + g], exb);
    }
}

// ---------------------------------------------------------------------------
// K4: one wave per segment; lane owns 2 of 128 dims; head = lane>>4.
// 4-way unrolled so 4 independent new_edges rows are in flight.
// ---------------------------------------------------------------------------
__global__ __launch_bounds__(256)
void k_gather(const float* __restrict__ new_edges, const float* __restrict__ ex,
              const float* __restrict__ denom, const int* __restrict__ offsets,
              const int* __restrict__ counts, const int* __restrict__ elist,
              float* __restrict__ out)
{
    const int gid  = blockIdx.x * 256 + threadIdx.x;
    const int seg  = gid >> 6;
    const int lane = threadIdx.x & 63;
    if (seg >= NSEG) return;

    const int start = offsets[seg];
    const int cnt   = counts[seg];
    const int h     = lane >> 4;
    const int doff  = lane * 2;

    float a0 = 0.f, a1 = 0.f;
    int i = 0;
    for (; i + 4 <= cnt; i += 4) {
        const int el0 = elist[start + i + 0];
        const int el1 = elist[start + i + 1];
        const int el2 = elist[start + i + 2];
        const int el3 = elist[start + i + 3];
        const float w0 = ex[(size_t)el0 * 4 + h];
        const float w1 = ex[(size_t)el1 * 4 + h];
        const float w2 = ex[(size_t)el2 * 4 + h];
        const float w3 = ex[(size_t)el3 * 4 + h];
        const float2 n0 = *reinterpret_cast<const float2*>(new_edges + (size_t)el0 * DD + doff);
        const float2 n1 = *reinterpret_cast<const float2*>(new_edges + (size_t)el1 * DD + doff);
        const float2 n2 = *reinterpret_cast<const float2*>(new_edges + (size_t)el2 * DD + doff);
        const float2 n3 = *reinterpret_cast<const float2*>(new_edges + (size_t)el3 * DD + doff);
        a0 = fmaf(n0.x, w0, a0); a1 = fmaf(n0.y, w0, a1);
        a0 = fmaf(n1.x, w1, a0); a1 = fmaf(n1.y, w1, a1);
        a0 = fmaf(n2.x, w2, a0); a1 = fmaf(n2.y, w2, a1);
        a0 = fmaf(n3.x, w3, a0); a1 = fmaf(n3.y, w3, a1);
    }
    for (; i < cnt; ++i) {
        const int el = elist[start + i];
        const float w = ex[(size_t)el * 4 + h];
        const float2 n = *reinterpret_cast<const float2*>(new_edges + (size_t)el * DD + doff);
        a0 = fmaf(n.x, w, a0); a1 = fmaf(n.y, w, a1);
    }
    const float scale = (cnt > 0) ? 1.0f / denom[seg * 4 + h] : 0.0f;
    float2 r; r.x = a0 * scale; r.y = a1 * scale;
    *reinterpret_cast<float2*>(out + (size_t)seg * DD + doff) = r;
}

// ---------------------------------------------------------------------------
extern "C" void kernel_launch(void* const* d_in, const int* in_sizes, int n_in,
                              void* d_out, int out_size, void* d_ws, size_t ws_size,
                              hipStream_t stream)
{
    const float* new_edges = (const float*)d_in[0];
    const float* edges     = (const float*)d_in[1];
    const float* pooled    = (const float*)d_in[2];
    const float* globs     = (const float*)d_in[3];
    const float* cndts     = (const float*)d_in[4];
    const float* W1        = (const float*)d_in[5];
    const float* b1        = (const float*)d_in[6];
    const float* W2        = (const float*)d_in[7];
    // b2 (d_in[8]) cancels in the per-head softmax — intentionally unused
    const int*   batch_idx = (const int*)d_in[9];
    const int*   recv_idx  = (const int*)d_in[10];
    float* out = (float*)d_out;

    char* ws = (char*)d_ws;
    float* ex       = (float*)(ws);                              // 16 MB
    float* denom    = (float*)(ws + (size_t)16 * 1024 * 1024);   // 1 MB
    char*  base17   = ws + (size_t)17 * 1024 * 1024;
    int*   counts   = (int*)(base17);                            // 256 KB
    int*   offs     = (int*)(base17 + 1 * 262144);
    int*   cursor   = (int*)(base17 + 2 * 262144);
    int*   tmp_excl = (int*)(base17 + 3 * 262144);
    int*   bsums    = (int*)(base17 + 4 * 262144);               // 1 KB
    int*   elist    = (int*)(ws + (size_t)18 * 1024 * 1024);     // 4 MB
    short* Wg       = (short*)(ws + (size_t)22 * 1024 * 1024);   // 49,152 B
    float* ctxtc    = (float*)(ws + (size_t)22 * 1024 * 1024 + 65536); // 64 KB

    // denom (1 MB) + counts (256 KB) contiguous: one memset
    hipMemsetAsync(denom, 0,
                   (size_t)NSEG * NH * sizeof(float) + (size_t)NSEG * sizeof(int),
                   stream);

    // index-only chain (independent of MLP)
    k_count<<<E_TOT / 256, 256, 0, stream>>>(batch_idx, recv_idx, counts);
    k_scan1<<<NSEG / 256, 256, 0, stream>>>(counts, tmp_excl, bsums);
    k_scan2<<<1, 256, 0, stream>>>(bsums);
    k_scan3<<<NSEG / 256, 256, 0, stream>>>(tmp_excl, bsums, offs, cursor);
    k_scatter<<<E_TOT / 256, 256, 0, stream>>>(batch_idx, recv_idx, cursor, elist);

    // MLP chain
    k_prep_w<<<96, 256, 0, stream>>>(W1, Wg);
    k_prep_ctx<<<64, 256, 0, stream>>>(W1, b1, globs, cndts, ctxtc);
    k_mlp_mfma<<<MLP_BLOCKS, 256, 0, stream>>>(pooled, edges, Wg, ctxtc, W2,
                                               batch_idx, recv_idx, ex, denom);

    // final weighted pool
    k_gather<<<(NSEG * 64) / 256, 256, 0, stream>>>(new_edges, ex, denom,
                                                    offs, counts, elist, out);
}

// Round 7
// 347.914 us; speedup vs baseline: 4.1588x; 2.7738x over previous
//
#include <hip/hip_runtime.h>
#include <hip/hip_bf16.h>
#include <cstdint>
#include <cstddef>

// Problem constants
#define E_TOT   1048576
#define BGR     64
#define NN      1024
#define DD      128
#define HID     256
#define NH      4
#define NSEG    65536
#define KDIM    96           // x in bf16; ctxt (globs/cndts) folded separately
#define NKCH    12           // KDIM/8 chunks
#define BM      64           // edges per tile
#define NTILES  (E_TOT/BM)   // 16384
#define GRIDM   512          // 2 blocks/CU
#define TPB     (NTILES/GRIDM) // 32 tiles per block

typedef __attribute__((ext_vector_type(8))) short s16x8;   // 8 bf16
typedef __attribute__((ext_vector_type(4))) float f32x4;

static __device__ __forceinline__ unsigned short f2bf_rn(float f) {
    unsigned u = __float_as_uint(f);
    unsigned r = u + 0x7FFF + ((u >> 16) & 1);   // round-to-nearest-even
    return (unsigned short)(r >> 16);
}

// ---------------------------------------------------------------------------
// Prep A: Wg [12 kchunk][256 hidden][8] bf16 = bf16(W1[0:96])  (MFMA A layout)
// ---------------------------------------------------------------------------
__global__ __launch_bounds__(256)
void k_prep_w(const float* __restrict__ W1, short* __restrict__ Wg) {
    int idx = blockIdx.x * 256 + threadIdx.x;        // < 12*256*8 = 24576
    int kchunk = idx >> 11;
    int n      = (idx >> 3) & 255;
    int j      = idx & 7;
    int k      = kchunk * 8 + j;                     // 0..95
    Wg[idx] = (short)f2bf_rn(W1[k * 256 + n]);
}

// ---------------------------------------------------------------------------
// Prep B: ctxtc[64][256] = b1 + globs[b]·W1[96:104] + cndts[b]·W1[104:112]
// ---------------------------------------------------------------------------
__global__ __launch_bounds__(256)
void k_prep_ctx(const float* __restrict__ W1, const float* __restrict__ b1,
                const float* __restrict__ globs, const float* __restrict__ cndts,
                float* __restrict__ ctxtc) {
    int b = blockIdx.x, j = threadIdx.x;
    float s = b1[j];
    #pragma unroll
    for (int g = 0; g < 8; ++g) s = fmaf(globs[b * 8 + g], W1[(96 + g) * 256 + j], s);
    #pragma unroll
    for (int c = 0; c < 8; ++c) s = fmaf(cndts[b * 8 + c], W1[(104 + c) * 256 + j], s);
    ctxtc[b * 256 + j] = s;
}

// ---------------------------------------------------------------------------
// Count edges per segment
// ---------------------------------------------------------------------------
__global__ __launch_bounds__(256)
void k_count(const int* __restrict__ batch_idx, const int* __restrict__ recv_idx,
             int* __restrict__ counts)
{
    int e = blockIdx.x * 256 + threadIdx.x;
    atomicAdd(&counts[batch_idx[e] * NN + recv_idx[e]], 1);
}

// ---------------------------------------------------------------------------
// Parallel exclusive scan of counts[65536]: 3 small kernels
// ---------------------------------------------------------------------------
__global__ __launch_bounds__(256)
void k_scan1(const int* __restrict__ counts, int* __restrict__ tmp_excl,
             int* __restrict__ blocksums)
{
    __shared__ int sh[256];
    const int t = threadIdx.x;
    const int gid = blockIdx.x * 256 + t;
    int c = counts[gid];
    sh[t] = c;
    __syncthreads();
    int v = c;
    for (int off = 1; off < 256; off <<= 1) {
        int u = (t >= off) ? sh[t - off] : 0;
        __syncthreads();
        v += u; sh[t] = v;
        __syncthreads();
    }
    tmp_excl[gid] = v - c;
    if (t == 255) blocksums[blockIdx.x] = v;
}

__global__ __launch_bounds__(256)
void k_scan2(int* __restrict__ blocksums)
{
    __shared__ int sh[256];
    const int t = threadIdx.x;
    int c = blocksums[t];
    sh[t] = c;
    __syncthreads();
    int v = c;
    for (int off = 1; off < 256; off <<= 1) {
        int u = (t >= off) ? sh[t - off] : 0;
        __syncthreads();
        v += u; sh[t] = v;
        __syncthreads();
    }
    blocksums[t] = v - c;
}

__global__ __launch_bounds__(256)
void k_scan3(const int* __restrict__ tmp_excl, const int* __restrict__ blocksums,
             int* __restrict__ offsets, int* __restrict__ cursor)
{
    const int gid = blockIdx.x * 256 + threadIdx.x;
    int v = tmp_excl[gid] + blocksums[blockIdx.x];
    offsets[gid] = v;
    cursor[gid]  = v;
}

// ---------------------------------------------------------------------------
// Scatter edge ids into per-segment lists (counting sort)
// ---------------------------------------------------------------------------
__global__ __launch_bounds__(256)
void k_scatter(const int* __restrict__ batch_idx, const int* __restrict__ recv_idx,
               int* __restrict__ cursor, int* __restrict__ elist)
{
    int e   = blockIdx.x * 256 + threadIdx.x;
    int seg = batch_idx[e] * NN + recv_idx[e];
    int pos = atomicAdd(&cursor[seg], 1);
    elist[pos] = e;
}

// ---------------------------------------------------------------------------
// Main fused MFMA kernel (K=96 bf16). BM=64 tile, 512 thr (8 waves =
// 2 edge-strips x 4 hidden-quarters). acc[4][2] = 32 VGPR (R5/R6 lesson:
// accumulator must be small). LDS 68KB -> 2 blocks/CU, 4 waves/SIMD.
// Each wf LDS read feeds 2 MFMAs. Layer-2 partial per hidden-quarter
// reduces in-wave (shfl ^16,^32) then combines via tiny plog[4][64][4].
// T14: next tile's global loads issue before K-loop, LDS writes after B.
// ---------------------------------------------------------------------------
__global__ __launch_bounds__(512, 4)
void k_mlp_mfma(const float* __restrict__ pooled, const float* __restrict__ edges,
                const short* __restrict__ Wg,     const float* __restrict__ ctxtc,
                const float* __restrict__ W2,
                const int* __restrict__ batch_idx, const int* __restrict__ recv_idx,
                float* __restrict__ ex_out, float* __restrict__ denom)
{
    __shared__ short Wl[NKCH * 256 * 8];        // 49152 B [kchunk][hidden][8]
    __shared__ short Xl[NKCH * BM * 8];         // 12288 B [kchunk][edge][8]
    __shared__ float sW2[256 * 4];              //  4096 B
    __shared__ float plog[4][BM][4];            //  4096 B [hq][edge][head]

    const int tid  = threadIdx.x;
    const int lane = tid & 63;
    const int wid  = tid >> 6;          // 0..7
    const int la   = lane & 15;
    const int g    = lane >> 4;         // 0..3 (k-octet select / acc row group)
    const int es   = wid & 1;           // edge strip: edges es*32..+31
    const int hq   = wid >> 1;          // hidden quarter: hq*64..+63

    // ---- prologue: W (layout prebuilt) + W2 into LDS ----
    {
        const float4* src = reinterpret_cast<const float4*>(Wg);
        float4* dst = reinterpret_cast<float4*>(Wl);
        #pragma unroll
        for (int i = 0; i < 6; ++i) dst[i * 512 + tid] = src[i * 512 + tid];
        if (tid < 256)
            *reinterpret_cast<float4*>(&sW2[tid * 4]) =
                reinterpret_cast<const float4*>(W2)[tid];
    }

    // staging: 768 units (64 edges x 12 kchunks); unit u -> edge u/12, kch u%12
    // thread handles u0 = tid, and u1 = tid+512 (tid < 256 only)
    const int u0 = tid;
    const int u1 = tid + 512;
    const int e_u0 = u0 / 12, k_u0 = u0 - e_u0 * 12;
    const int e_u1 = u1 / 12, k_u1 = u1 - e_u1 * 12;

    // ---- stage tile0 ----
    {
        const int e0 = blockIdx.x * TPB * BM;
        {
            const int eg = e0 + e_u0;
            const float* p = (k_u0 < 4) ? (pooled + (size_t)eg * 32 + k_u0 * 8)
                                        : (edges + (size_t)eg * 64 + (k_u0 - 4) * 8);
            float4 v0 = reinterpret_cast<const float4*>(p)[0];
            float4 v1 = reinterpret_cast<const float4*>(p)[1];
            float vals[8] = {v0.x,v0.y,v0.z,v0.w,v1.x,v1.y,v1.z,v1.w};
            s16x8 hv;
            #pragma unroll
            for (int i = 0; i < 8; ++i) hv[i] = (short)f2bf_rn(vals[i]);
            *reinterpret_cast<s16x8*>(&Xl[(k_u0 * BM + e_u0) * 8]) = hv;
        }
        if (tid < 256) {
            const int eg = e0 + e_u1;
            const float* p = (k_u1 < 4) ? (pooled + (size_t)eg * 32 + k_u1 * 8)
                                        : (edges + (size_t)eg * 64 + (k_u1 - 4) * 8);
            float4 v0 = reinterpret_cast<const float4*>(p)[0];
            float4 v1 = reinterpret_cast<const float4*>(p)[1];
            float vals[8] = {v0.x,v0.y,v0.z,v0.w,v1.x,v1.y,v1.z,v1.w};
            s16x8 hv;
            #pragma unroll
            for (int i = 0; i < 8; ++i) hv[i] = (short)f2bf_rn(vals[i]);
            *reinterpret_cast<s16x8*>(&Xl[(k_u1 * BM + e_u1) * 8]) = hv;
        }
    }
    __syncthreads();

    for (int t = 0; t < TPB; ++t) {
        const int e0 = (blockIdx.x * TPB + t) * BM;
        const bool has_next = (t + 1 < TPB);

        // ---- T14: issue next tile's global loads (held in 4 float4) ----
        float4 sa0, sa1, sb0, sb1;
        if (has_next) {
            const int en = e0 + BM;
            {
                const int eg = en + e_u0;
                const float* p = (k_u0 < 4) ? (pooled + (size_t)eg * 32 + k_u0 * 8)
                                            : (edges + (size_t)eg * 64 + (k_u0 - 4) * 8);
                sa0 = reinterpret_cast<const float4*>(p)[0];
                sa1 = reinterpret_cast<const float4*>(p)[1];
            }
            if (tid < 256) {
                const int eg = en + e_u1;
                const float* p = (k_u1 < 4) ? (pooled + (size_t)eg * 32 + k_u1 * 8)
                                            : (edges + (size_t)eg * 64 + (k_u1 - 4) * 8);
                sb0 = reinterpret_cast<const float4*>(p)[0];
                sb1 = reinterpret_cast<const float4*>(p)[1];
            }
        }

        // ---- K-loop: 3 ks x (4 hf x 2 ef) MFMA; wf read feeds 2 MFMAs ----
        f32x4 acc[4][2];
        #pragma unroll
        for (int i = 0; i < 4; ++i) {
            acc[i][0] = (f32x4){0.f, 0.f, 0.f, 0.f};
            acc[i][1] = (f32x4){0.f, 0.f, 0.f, 0.f};
        }
        #pragma unroll
        for (int ks = 0; ks < 3; ++ks) {
            const int kb = ks * 4 + g;
            const s16x8 xf0 = *reinterpret_cast<const s16x8*>(
                &Xl[(kb * BM + es * 32 + la) * 8]);
            const s16x8 xf1 = *reinterpret_cast<const s16x8*>(
                &Xl[(kb * BM + es * 32 + 16 + la) * 8]);
            const short* wrow = &Wl[(kb * 256 + hq * 64 + la) * 8];
            #pragma unroll
            for (int hf = 0; hf < 4; ++hf) {
                s16x8 wf = *reinterpret_cast<const s16x8*>(wrow + hf * 128);
                acc[hf][0] = __builtin_amdgcn_mfma_f32_16x16x32_bf16(wf, xf0, acc[hf][0], 0, 0, 0);
                acc[hf][1] = __builtin_amdgcn_mfma_f32_16x16x32_bf16(wf, xf1, acc[hf][1], 0, 0, 0);
            }
        }

        // ---- epi1: +ctxt, leaky, layer-2 partials over this hq, wave reduce ----
        {
            const int ea = e0 + es * 32 + la;
            const int eb = ea + 16;
            const int ba = batch_idx[ea];
            const int bb = batch_idx[eb];
            const float* cxa_base = &ctxtc[(size_t)ba * 256 + hq * 64 + g * 4];
            const float* cxb_base = &ctxtc[(size_t)bb * 256 + hq * 64 + g * 4];
            float pa0 = 0.f, pa1 = 0.f, pa2 = 0.f, pa3 = 0.f;
            float pb0 = 0.f, pb1 = 0.f, pb2 = 0.f, pb3 = 0.f;
            #pragma unroll
            for (int hf = 0; hf < 4; ++hf) {
                const float4 cxa = *reinterpret_cast<const float4*>(cxa_base + hf * 16);
                const float4 cxb = *reinterpret_cast<const float4*>(cxb_base + hf * 16);
                const float cxaa[4] = {cxa.x, cxa.y, cxa.z, cxa.w};
                const float cxba[4] = {cxb.x, cxb.y, cxb.z, cxb.w};
                #pragma unroll
                for (int r = 0; r < 4; ++r) {
                    const int j = hq * 64 + hf * 16 + g * 4 + r;
                    const float4 w2v = *reinterpret_cast<const float4*>(&sW2[j * 4]);
                    float sa = acc[hf][0][r] + cxaa[r];
                    float ha = fmaxf(sa, 0.1f * sa);     // leaky_relu(0.1)
                    float sb = acc[hf][1][r] + cxba[r];
                    float hb = fmaxf(sb, 0.1f * sb);
                    pa0 = fmaf(ha, w2v.x, pa0); pb0 = fmaf(hb, w2v.x, pb0);
                    pa1 = fmaf(ha, w2v.y, pa1); pb1 = fmaf(hb, w2v.y, pb1);
                    pa2 = fmaf(ha, w2v.z, pa2); pb2 = fmaf(hb, w2v.z, pb2);
                    pa3 = fmaf(ha, w2v.w, pa3); pb3 = fmaf(hb, w2v.w, pb3);
                }
            }
            pa0 += __shfl_xor(pa0, 16); pa0 += __shfl_xor(pa0, 32);
            pa1 += __shfl_xor(pa1, 16); pa1 += __shfl_xor(pa1, 32);
            pa2 += __shfl_xor(pa2, 16); pa2 += __shfl_xor(pa2, 32);
            pa3 += __shfl_xor(pa3, 16); pa3 += __shfl_xor(pa3, 32);
            pb0 += __shfl_xor(pb0, 16); pb0 += __shfl_xor(pb0, 32);
            pb1 += __shfl_xor(pb1, 16); pb1 += __shfl_xor(pb1, 32);
            pb2 += __shfl_xor(pb2, 16); pb2 += __shfl_xor(pb2, 32);
            pb3 += __shfl_xor(pb3, 16); pb3 += __shfl_xor(pb3, 32);
            float pla = (g == 0) ? pa0 : (g == 1) ? pa1 : (g == 2) ? pa2 : pa3;
            float plb = (g == 0) ? pb0 : (g == 1) ? pb1 : (g == 2) ? pb2 : pb3;
            plog[hq][es * 32 + la][g]      = pla;
            plog[hq][es * 32 + 16 + la][g] = plb;
        }
        __syncthreads();   // B: Xl(t) reads done, plog visible

        // ---- write next tile into Xl ----
        if (has_next) {
            {
                float vals[8] = {sa0.x,sa0.y,sa0.z,sa0.w,sa1.x,sa1.y,sa1.z,sa1.w};
                s16x8 hv;
                #pragma unroll
                for (int i = 0; i < 8; ++i) hv[i] = (short)f2bf_rn(vals[i]);
                *reinterpret_cast<s16x8*>(&Xl[(k_u0 * BM + e_u0) * 8]) = hv;
            }
            if (tid < 256) {
                float vals[8] = {sb0.x,sb0.y,sb0.z,sb0.w,sb1.x,sb1.y,sb1.z,sb1.w};
                s16x8 hv;
                #pragma unroll
                for (int i = 0; i < 8; ++i) hv[i] = (short)f2bf_rn(vals[i]);
                *reinterpret_cast<s16x8*>(&Xl[(k_u1 * BM + e_u1) * 8]) = hv;
            }
        }

        // ---- epi2: combine 4 quarters, exp, store, atomics (tid<256) ----
        if (tid < 256) {
            const int e = tid >> 2;
            const int h = tid & 3;
            const int eg = e0 + e;
            float lg = plog[0][e][h] + plog[1][e][h] + plog[2][e][h] + plog[3][e][h];
            float exv = __expf(lg);
            ex_out[(size_t)eg * 4 + h] = exv;
            const int seg = batch_idx[eg] * NN + recv_idx[eg];
            atomicAdd(&denom[seg * 4 + h], exv);
        }
        __syncthreads();   // C: Xl(t+1) ready, plog consumed
    }
}

// ---------------------------------------------------------------------------
// K4: one wave per segment; lane owns 2 of 128 dims; head = lane>>4.
// 4-way unrolled so 4 independent new_edges rows are in flight.
// ---------------------------------------------------------------------------
__global__ __launch_bounds__(256)
void k_gather(const float* __restrict__ new_edges, const float* __restrict__ ex,
              const float* __restrict__ denom, const int* __restrict__ offsets,
              const int* __restrict__ counts, const int* __restrict__ elist,
              float* __restrict__ out)
{
    const int gid  = blockIdx.x * 256 + threadIdx.x;
    const int seg  = gid >> 6;
    const int lane = threadIdx.x & 63;
    if (seg >= NSEG) return;

    const int start = offsets[seg];
    const int cnt   = counts[seg];
    const int h     = lane >> 4;
    const int doff  = lane * 2;

    float a0 = 0.f, a1 = 0.f;
    int i = 0;
    for (; i + 4 <= cnt; i += 4) {
        const int el0 = elist[start + i + 0];
        const int el1 = elist[start + i + 1];
        const int el2 = elist[start + i + 2];
        const int el3 = elist[start + i + 3];
        const float w0 = ex[(size_t)el0 * 4 + h];
        const float w1 = ex[(size_t)el1 * 4 + h];
        const float w2 = ex[(size_t)el2 * 4 + h];
        const float w3 = ex[(size_t)el3 * 4 + h];
        const float2 n0 = *reinterpret_cast<const float2*>(new_edges + (size_t)el0 * DD + doff);
        const float2 n1 = *reinterpret_cast<const float2*>(new_edges + (size_t)el1 * DD + doff);
        const float2 n2 = *reinterpret_cast<const float2*>(new_edges + (size_t)el2 * DD + doff);
        const float2 n3 = *reinterpret_cast<const float2*>(new_edges + (size_t)el3 * DD + doff);
        a0 = fmaf(n0.x, w0, a0); a1 = fmaf(n0.y, w0, a1);
        a0 = fmaf(n1.x, w1, a0); a1 = fmaf(n1.y, w1, a1);
        a0 = fmaf(n2.x, w2, a0); a1 = fmaf(n2.y, w2, a1);
        a0 = fmaf(n3.x, w3, a0); a1 = fmaf(n3.y, w3, a1);
    }
    for (; i < cnt; ++i) {
        const int el = elist[start + i];
        const float w = ex[(size_t)el * 4 + h];
        const float2 n = *reinterpret_cast<const float2*>(new_edges + (size_t)el * DD + doff);
        a0 = fmaf(n.x, w, a0); a1 = fmaf(n.y, w, a1);
    }
    const float scale = (cnt > 0) ? 1.0f / denom[seg * 4 + h] : 0.0f;
    float2 r; r.x = a0 * scale; r.y = a1 * scale;
    *reinterpret_cast<float2*>(out + (size_t)seg * DD + doff) = r;
}

// ---------------------------------------------------------------------------
extern "C" void kernel_launch(void* const* d_in, const int* in_sizes, int n_in,
                              void* d_out, int out_size, void* d_ws, size_t ws_size,
                              hipStream_t stream)
{
    const float* new_edges = (const float*)d_in[0];
    const float* edges     = (const float*)d_in[1];
    const float* pooled    = (const float*)d_in[2];
    const float* globs     = (const float*)d_in[3];
    const float* cndts     = (const float*)d_in[4];
    const float* W1        = (const float*)d_in[5];
    const float* b1        = (const float*)d_in[6];
    const float* W2        = (const float*)d_in[7];
    // b2 (d_in[8]) cancels in the per-head softmax — intentionally unused
    const int*   batch_idx = (const int*)d_in[9];
    const int*   recv_idx  = (const int*)d_in[10];
    float* out = (float*)d_out;

    char* ws = (char*)d_ws;
    float* ex       = (float*)(ws);                              // 16 MB
    float* denom    = (float*)(ws + (size_t)16 * 1024 * 1024);   // 1 MB
    char*  base17   = ws + (size_t)17 * 1024 * 1024;
    int*   counts   = (int*)(base17);                            // 256 KB
    int*   offs     = (int*)(base17 + 1 * 262144);
    int*   cursor   = (int*)(base17 + 2 * 262144);
    int*   tmp_excl = (int*)(base17 + 3 * 262144);
    int*   bsums    = (int*)(base17 + 4 * 262144);               // 1 KB
    int*   elist    = (int*)(ws + (size_t)18 * 1024 * 1024);     // 4 MB
    short* Wg       = (short*)(ws + (size_t)22 * 1024 * 1024);   // 49,152 B
    float* ctxtc    = (float*)(ws + (size_t)22 * 1024 * 1024 + 65536); // 64 KB

    // denom (1 MB) + counts (256 KB) contiguous: one memset
    hipMemsetAsync(denom, 0,
                   (size_t)NSEG * NH * sizeof(float) + (size_t)NSEG * sizeof(int),
                   stream);

    // index-only chain (independent of MLP)
    k_count<<<E_TOT / 256, 256, 0, stream>>>(batch_idx, recv_idx, counts);
    k_scan1<<<NSEG / 256, 256, 0, stream>>>(counts, tmp_excl, bsums);
    k_scan2<<<1, 256, 0, stream>>>(bsums);
    k_scan3<<<NSEG / 256, 256, 0, stream>>>(tmp_excl, bsums, offs, cursor);
    k_scatter<<<E_TOT / 256, 256, 0, stream>>>(batch_idx, recv_idx, cursor, elist);

    // MLP chain
    k_prep_w<<<96, 256, 0, stream>>>(W1, Wg);
    k_prep_ctx<<<64, 256, 0, stream>>>(W1, b1, globs, cndts, ctxtc);
    k_mlp_mfma<<<GRIDM, 512, 0, stream>>>(pooled, edges, Wg, ctxtc, W2,
                                          batch_idx, recv_idx, ex, denom);

    // final weighted pool
    k_gather<<<(NSEG * 64) / 256, 256, 0, stream>>>(new_edges, ex, denom,
                                                    offs, counts, elist, out);
}

// Round 8
// 325.584 us; speedup vs baseline: 4.4440x; 1.0686x over previous
//
#include <hip/hip_runtime.h>
#include <hip/hip_bf16.h>
#include <cstdint>
#include <cstddef>

// Problem constants
#define E_TOT   1048576
#define BGR     64
#define NN      1024
#define DD      128
#define HID     256
#define NH      4
#define NSEG    65536
#define KDIM    96           // x in bf16; ctxt (globs/cndts) folded separately
#define NKCH    12           // KDIM/8 chunks
#define BM      64           // edges per tile
#define NTILES  (E_TOT/BM)   // 16384
#define GRIDM   512          // 2 blocks/CU
#define TPB     (NTILES/GRIDM) // 32 tiles per block

typedef __attribute__((ext_vector_type(8))) short s16x8;   // 8 bf16
typedef __attribute__((ext_vector_type(4))) float f32x4;

static __device__ __forceinline__ unsigned short f2bf_rn(float f) {
    unsigned u = __float_as_uint(f);
    unsigned r = u + 0x7FFF + ((u >> 16) & 1);   // round-to-nearest-even
    return (unsigned short)(r >> 16);
}

// ---------------------------------------------------------------------------
// k_misc: grid-partitioned fusion of three independent prep passes
//   blocks [0, 4096)        : per-segment histogram (count)
//   blocks [4096, 4192)     : Wg [12][256][8] bf16 = bf16(W1[0:96]) MFMA layout
//   blocks [4192, 4256)     : ctxtc[64][256] = b1 + globs·W1[96:104] + cndts·W1[104:112]
// ---------------------------------------------------------------------------
__global__ __launch_bounds__(256)
void k_misc(const float* __restrict__ W1, const float* __restrict__ b1,
            const float* __restrict__ globs, const float* __restrict__ cndts,
            const int* __restrict__ batch_idx, const int* __restrict__ recv_idx,
            short* __restrict__ Wg, float* __restrict__ ctxtc,
            int* __restrict__ counts)
{
    const int bid = blockIdx.x;
    const int tid = threadIdx.x;
    if (bid < 4096) {
        int e = bid * 256 + tid;
        atomicAdd(&counts[batch_idx[e] * NN + recv_idx[e]], 1);
    } else if (bid < 4096 + 96) {
        int idx = (bid - 4096) * 256 + tid;          // < 24576
        int kchunk = idx >> 11;
        int n      = (idx >> 3) & 255;
        int j      = idx & 7;
        int k      = kchunk * 8 + j;                 // 0..95
        Wg[idx] = (short)f2bf_rn(W1[k * 256 + n]);
    } else {
        int b = bid - 4192, j = tid;
        float s = b1[j];
        #pragma unroll
        for (int g = 0; g < 8; ++g) s = fmaf(globs[b * 8 + g], W1[(96 + g) * 256 + j], s);
        #pragma unroll
        for (int c = 0; c < 8; ++c) s = fmaf(cndts[b * 8 + c], W1[(104 + c) * 256 + j], s);
        ctxtc[b * 256 + j] = s;
    }
}

// ---------------------------------------------------------------------------
// scan1: per-256-chunk exclusive scan + chunk totals
// ---------------------------------------------------------------------------
__global__ __launch_bounds__(256)
void k_scan1(const int* __restrict__ counts, int* __restrict__ tmp_excl,
             int* __restrict__ blocksums)
{
    __shared__ int sh[256];
    const int t = threadIdx.x;
    const int gid = blockIdx.x * 256 + t;
    int c = counts[gid];
    sh[t] = c;
    __syncthreads();
    int v = c;
    for (int off = 1; off < 256; off <<= 1) {
        int u = (t >= off) ? sh[t - off] : 0;
        __syncthreads();
        v += u; sh[t] = v;
        __syncthreads();
    }
    tmp_excl[gid] = v - c;
    if (t == 255) blocksums[blockIdx.x] = v;
}

// ---------------------------------------------------------------------------
// scan3: each block derives its own base by reducing blocksums[0..bid)
// (1 KB, L2-hot) — replaces the former single-block scan2 kernel.
// ---------------------------------------------------------------------------
__global__ __launch_bounds__(256)
void k_scan3(const int* __restrict__ tmp_excl, const int* __restrict__ blocksums,
             int* __restrict__ offsets, int* __restrict__ cursor)
{
    __shared__ int swv[4];
    const int t = threadIdx.x;
    const int bid = blockIdx.x;
    int v = (t < bid) ? blocksums[t] : 0;
    #pragma unroll
    for (int off = 1; off < 64; off <<= 1) v += __shfl_xor(v, off);
    if ((t & 63) == 0) swv[t >> 6] = v;
    __syncthreads();
    const int base = swv[0] + swv[1] + swv[2] + swv[3];
    const int gid = bid * 256 + t;
    int o = tmp_excl[gid] + base;
    offsets[gid] = o;
    cursor[gid]  = o;
}

// ---------------------------------------------------------------------------
// Main fused MFMA kernel (K=96 bf16). BM=64 tile, 512 thr (8 waves =
// 2 edge-strips x 4 hidden-quarters). acc[4][2] = 32 VGPR (R5/R6 lesson:
// accumulator must be small). LDS 68KB -> 2 blocks/CU, 4 waves/SIMD.
// Each wf LDS read feeds 2 MFMAs. Layer-2 partial per hidden-quarter
// reduces in-wave (shfl ^16,^32) then combines via tiny plog[4][64][4].
// T14: next tile's global loads issue before K-loop, LDS writes after B.
// R8: counting-sort scatter fused into epi2 (h==0 lane).
// ---------------------------------------------------------------------------
__global__ __launch_bounds__(512, 4)
void k_mlp_mfma(const float* __restrict__ pooled, const float* __restrict__ edges,
                const short* __restrict__ Wg,     const float* __restrict__ ctxtc,
                const float* __restrict__ W2,
                const int* __restrict__ batch_idx, const int* __restrict__ recv_idx,
                float* __restrict__ ex_out, float* __restrict__ denom,
                int* __restrict__ cursor, int* __restrict__ elist)
{
    __shared__ short Wl[NKCH * 256 * 8];        // 49152 B [kchunk][hidden][8]
    __shared__ short Xl[NKCH * BM * 8];         // 12288 B [kchunk][edge][8]
    __shared__ float sW2[256 * 4];              //  4096 B
    __shared__ float plog[4][BM][4];            //  4096 B [hq][edge][head]

    const int tid  = threadIdx.x;
    const int lane = tid & 63;
    const int wid  = tid >> 6;          // 0..7
    const int la   = lane & 15;
    const int g    = lane >> 4;         // 0..3 (k-octet select / acc row group)
    const int es   = wid & 1;           // edge strip: edges es*32..+31
    const int hq   = wid >> 1;          // hidden quarter: hq*64..+63

    // ---- prologue: W (layout prebuilt) + W2 into LDS ----
    {
        const float4* src = reinterpret_cast<const float4*>(Wg);
        float4* dst = reinterpret_cast<float4*>(Wl);
        #pragma unroll
        for (int i = 0; i < 6; ++i) dst[i * 512 + tid] = src[i * 512 + tid];
        if (tid < 256)
            *reinterpret_cast<float4*>(&sW2[tid * 4]) =
                reinterpret_cast<const float4*>(W2)[tid];
    }

    // staging: 768 units (64 edges x 12 kchunks); unit u -> edge u/12, kch u%12
    const int u0 = tid;
    const int u1 = tid + 512;
    const int e_u0 = u0 / 12, k_u0 = u0 - e_u0 * 12;
    const int e_u1 = u1 / 12, k_u1 = u1 - e_u1 * 12;

    // ---- stage tile0 ----
    {
        const int e0 = blockIdx.x * TPB * BM;
        {
            const int eg = e0 + e_u0;
            const float* p = (k_u0 < 4) ? (pooled + (size_t)eg * 32 + k_u0 * 8)
                                        : (edges + (size_t)eg * 64 + (k_u0 - 4) * 8);
            float4 v0 = reinterpret_cast<const float4*>(p)[0];
            float4 v1 = reinterpret_cast<const float4*>(p)[1];
            float vals[8] = {v0.x,v0.y,v0.z,v0.w,v1.x,v1.y,v1.z,v1.w};
            s16x8 hv;
            #pragma unroll
            for (int i = 0; i < 8; ++i) hv[i] = (short)f2bf_rn(vals[i]);
            *reinterpret_cast<s16x8*>(&Xl[(k_u0 * BM + e_u0) * 8]) = hv;
        }
        if (tid < 256) {
            const int eg = e0 + e_u1;
            const float* p = (k_u1 < 4) ? (pooled + (size_t)eg * 32 + k_u1 * 8)
                                        : (edges + (size_t)eg * 64 + (k_u1 - 4) * 8);
            float4 v0 = reinterpret_cast<const float4*>(p)[0];
            float4 v1 = reinterpret_cast<const float4*>(p)[1];
            float vals[8] = {v0.x,v0.y,v0.z,v0.w,v1.x,v1.y,v1.z,v1.w};
            s16x8 hv;
            #pragma unroll
            for (int i = 0; i < 8; ++i) hv[i] = (short)f2bf_rn(vals[i]);
            *reinterpret_cast<s16x8*>(&Xl[(k_u1 * BM + e_u1) * 8]) = hv;
        }
    }
    __syncthreads();

    for (int t = 0; t < TPB; ++t) {
        const int e0 = (blockIdx.x * TPB + t) * BM;
        const bool has_next = (t + 1 < TPB);

        // ---- T14: issue next tile's global loads (held in 4 float4) ----
        float4 sa0, sa1, sb0, sb1;
        if (has_next) {
            const int en = e0 + BM;
            {
                const int eg = en + e_u0;
                const float* p = (k_u0 < 4) ? (pooled + (size_t)eg * 32 + k_u0 * 8)
                                            : (edges + (size_t)eg * 64 + (k_u0 - 4) * 8);
                sa0 = reinterpret_cast<const float4*>(p)[0];
                sa1 = reinterpret_cast<const float4*>(p)[1];
            }
            if (tid < 256) {
                const int eg = en + e_u1;
                const float* p = (k_u1 < 4) ? (pooled + (size_t)eg * 32 + k_u1 * 8)
                                            : (edges + (size_t)eg * 64 + (k_u1 - 4) * 8);
                sb0 = reinterpret_cast<const float4*>(p)[0];
                sb1 = reinterpret_cast<const float4*>(p)[1];
            }
        }

        // ---- K-loop: 3 ks x (4 hf x 2 ef) MFMA; wf read feeds 2 MFMAs ----
        f32x4 acc[4][2];
        #pragma unroll
        for (int i = 0; i < 4; ++i) {
            acc[i][0] = (f32x4){0.f, 0.f, 0.f, 0.f};
            acc[i][1] = (f32x4){0.f, 0.f, 0.f, 0.f};
        }
        #pragma unroll
        for (int ks = 0; ks < 3; ++ks) {
            const int kb = ks * 4 + g;
            const s16x8 xf0 = *reinterpret_cast<const s16x8*>(
                &Xl[(kb * BM + es * 32 + la) * 8]);
            const s16x8 xf1 = *reinterpret_cast<const s16x8*>(
                &Xl[(kb * BM + es * 32 + 16 + la) * 8]);
            const short* wrow = &Wl[(kb * 256 + hq * 64 + la) * 8];
            #pragma unroll
            for (int hf = 0; hf < 4; ++hf) {
                s16x8 wf = *reinterpret_cast<const s16x8*>(wrow + hf * 128);
                acc[hf][0] = __builtin_amdgcn_mfma_f32_16x16x32_bf16(wf, xf0, acc[hf][0], 0, 0, 0);
                acc[hf][1] = __builtin_amdgcn_mfma_f32_16x16x32_bf16(wf, xf1, acc[hf][1], 0, 0, 0);
            }
        }

        // ---- epi1: +ctxt, leaky, layer-2 partials over this hq, wave reduce ----
        {
            const int ea = e0 + es * 32 + la;
            const int eb = ea + 16;
            const int ba = batch_idx[ea];
            const int bb = batch_idx[eb];
            const float* cxa_base = &ctxtc[(size_t)ba * 256 + hq * 64 + g * 4];
            const float* cxb_base = &ctxtc[(size_t)bb * 256 + hq * 64 + g * 4];
            float pa0 = 0.f, pa1 = 0.f, pa2 = 0.f, pa3 = 0.f;
            float pb0 = 0.f, pb1 = 0.f, pb2 = 0.f, pb3 = 0.f;
            #pragma unroll
            for (int hf = 0; hf < 4; ++hf) {
                const float4 cxa = *reinterpret_cast<const float4*>(cxa_base + hf * 16);
                const float4 cxb = *reinterpret_cast<const float4*>(cxb_base + hf * 16);
                const float cxaa[4] = {cxa.x, cxa.y, cxa.z, cxa.w};
                const float cxba[4] = {cxb.x, cxb.y, cxb.z, cxb.w};
                #pragma unroll
                for (int r = 0; r < 4; ++r) {
                    const int j = hq * 64 + hf * 16 + g * 4 + r;
                    const float4 w2v = *reinterpret_cast<const float4*>(&sW2[j * 4]);
                    float sa = acc[hf][0][r] + cxaa[r];
                    float ha = fmaxf(sa, 0.1f * sa);     // leaky_relu(0.1)
                    float sb = acc[hf][1][r] + cxba[r];
                    float hb = fmaxf(sb, 0.1f * sb);
                    pa0 = fmaf(ha, w2v.x, pa0); pb0 = fmaf(hb, w2v.x, pb0);
                    pa1 = fmaf(ha, w2v.y, pa1); pb1 = fmaf(hb, w2v.y, pb1);
                    pa2 = fmaf(ha, w2v.z, pa2); pb2 = fmaf(hb, w2v.z, pb2);
                    pa3 = fmaf(ha, w2v.w, pa3); pb3 = fmaf(hb, w2v.w, pb3);
                }
            }
            pa0 += __shfl_xor(pa0, 16); pa0 += __shfl_xor(pa0, 32);
            pa1 += __shfl_xor(pa1, 16); pa1 += __shfl_xor(pa1, 32);
            pa2 += __shfl_xor(pa2, 16); pa2 += __shfl_xor(pa2, 32);
            pa3 += __shfl_xor(pa3, 16); pa3 += __shfl_xor(pa3, 32);
            pb0 += __shfl_xor(pb0, 16); pb0 += __shfl_xor(pb0, 32);
            pb1 += __shfl_xor(pb1, 16); pb1 += __shfl_xor(pb1, 32);
            pb2 += __shfl_xor(pb2, 16); pb2 += __shfl_xor(pb2, 32);
            pb3 += __shfl_xor(pb3, 16); pb3 += __shfl_xor(pb3, 32);
            float pla = (g == 0) ? pa0 : (g == 1) ? pa1 : (g == 2) ? pa2 : pa3;
            float plb = (g == 0) ? pb0 : (g == 1) ? pb1 : (g == 2) ? pb2 : pb3;
            plog[hq][es * 32 + la][g]      = pla;
            plog[hq][es * 32 + 16 + la][g] = plb;
        }
        __syncthreads();   // B: Xl(t) reads done, plog visible

        // ---- write next tile into Xl ----
        if (has_next) {
            {
                float vals[8] = {sa0.x,sa0.y,sa0.z,sa0.w,sa1.x,sa1.y,sa1.z,sa1.w};
                s16x8 hv;
                #pragma unroll
                for (int i = 0; i < 8; ++i) hv[i] = (short)f2bf_rn(vals[i]);
                *reinterpret_cast<s16x8*>(&Xl[(k_u0 * BM + e_u0) * 8]) = hv;
            }
            if (tid < 256) {
                float vals[8] = {sb0.x,sb0.y,sb0.z,sb0.w,sb1.x,sb1.y,sb1.z,sb1.w};
                s16x8 hv;
                #pragma unroll
                for (int i = 0; i < 8; ++i) hv[i] = (short)f2bf_rn(vals[i]);
                *reinterpret_cast<s16x8*>(&Xl[(k_u1 * BM + e_u1) * 8]) = hv;
            }
        }

        // ---- epi2: combine quarters, exp, store, denom atomic; h==0 lane
        //      also does the counting-sort scatter (fused former k_scatter) ----
        if (tid < 256) {
            const int e = tid >> 2;
            const int h = tid & 3;
            const int eg = e0 + e;
            float lg = plog[0][e][h] + plog[1][e][h] + plog[2][e][h] + plog[3][e][h];
            float exv = __expf(lg);
            ex_out[(size_t)eg * 4 + h] = exv;
            const int seg = batch_idx[eg] * NN + recv_idx[eg];
            atomicAdd(&denom[seg * 4 + h], exv);
            if (h == 0) {
                int pos = atomicAdd(&cursor[seg], 1);
                elist[pos] = eg;
            }
        }
        __syncthreads();   // C: Xl(t+1) ready, plog consumed
    }
}

// ---------------------------------------------------------------------------
// K4: one wave per segment; lane owns 2 of 128 dims; head = lane>>4.
// 4-way unrolled so 4 independent new_edges rows are in flight.
// ---------------------------------------------------------------------------
__global__ __launch_bounds__(256)
void k_gather(const float* __restrict__ new_edges, const float* __restrict__ ex,
              const float* __restrict__ denom, const int* __restrict__ offsets,
              const int* __restrict__ counts, const int* __restrict__ elist,
              float* __restrict__ out)
{
    const int gid  = blockIdx.x * 256 + threadIdx.x;
    const int seg  = gid >> 6;
    const int lane = threadIdx.x & 63;
    if (seg >= NSEG) return;

    const int start = offsets[seg];
    const int cnt   = counts[seg];
    const int h     = lane >> 4;
    const int doff  = lane * 2;

    float a0 = 0.f, a1 = 0.f;
    int i = 0;
    for (; i + 4 <= cnt; i += 4) {
        const int el0 = elist[start + i + 0];
        const int el1 = elist[start + i + 1];
        const int el2 = elist[start + i + 2];
        const int el3 = elist[start + i + 3];
        const float w0 = ex[(size_t)el0 * 4 + h];
        const float w1 = ex[(size_t)el1 * 4 + h];
        const float w2 = ex[(size_t)el2 * 4 + h];
        const float w3 = ex[(size_t)el3 * 4 + h];
        const float2 n0 = *reinterpret_cast<const float2*>(new_edges + (size_t)el0 * DD + doff);
        const float2 n1 = *reinterpret_cast<const float2*>(new_edges + (size_t)el1 * DD + doff);
        const float2 n2 = *reinterpret_cast<const float2*>(new_edges + (size_t)el2 * DD + doff);
        const float2 n3 = *reinterpret_cast<const float2*>(new_edges + (size_t)el3 * DD + doff);
        a0 = fmaf(n0.x, w0, a0); a1 = fmaf(n0.y, w0, a1);
        a0 = fmaf(n1.x, w1, a0); a1 = fmaf(n1.y, w1, a1);
        a0 = fmaf(n2.x, w2, a0); a1 = fmaf(n2.y, w2, a1);
        a0 = fmaf(n3.x, w3, a0); a1 = fmaf(n3.y, w3, a1);
    }
    for (; i < cnt; ++i) {
        const int el = elist[start + i];
        const float w = ex[(size_t)el * 4 + h];
        const float2 n = *reinterpret_cast<const float2*>(new_edges + (size_t)el * DD + doff);
        a0 = fmaf(n.x, w, a0); a1 = fmaf(n.y, w, a1);
    }
    const float scale = (cnt > 0) ? 1.0f / denom[seg * 4 + h] : 0.0f;
    float2 r; r.x = a0 * scale; r.y = a1 * scale;
    *reinterpret_cast<float2*>(out + (size_t)seg * DD + doff) = r;
}

// ---------------------------------------------------------------------------
extern "C" void kernel_launch(void* const* d_in, const int* in_sizes, int n_in,
                              void* d_out, int out_size, void* d_ws, size_t ws_size,
                              hipStream_t stream)
{
    const float* new_edges = (const float*)d_in[0];
    const float* edges     = (const float*)d_in[1];
    const float* pooled    = (const float*)d_in[2];
    const float* globs     = (const float*)d_in[3];
    const float* cndts     = (const float*)d_in[4];
    const float* W1        = (const float*)d_in[5];
    const float* b1        = (const float*)d_in[6];
    const float* W2        = (const float*)d_in[7];
    // b2 (d_in[8]) cancels in the per-head softmax — intentionally unused
    const int*   batch_idx = (const int*)d_in[9];
    const int*   recv_idx  = (const int*)d_in[10];
    float* out = (float*)d_out;

    char* ws = (char*)d_ws;
    float* ex       = (float*)(ws);                              // 16 MB
    float* denom    = (float*)(ws + (size_t)16 * 1024 * 1024);   // 1 MB
    char*  base17   = ws + (size_t)17 * 1024 * 1024;
    int*   counts   = (int*)(base17);                            // 256 KB
    int*   offs     = (int*)(base17 + 1 * 262144);
    int*   cursor   = (int*)(base17 + 2 * 262144);
    int*   tmp_excl = (int*)(base17 + 3 * 262144);
    int*   bsums    = (int*)(base17 + 4 * 262144);               // 1 KB
    int*   elist    = (int*)(ws + (size_t)18 * 1024 * 1024);     // 4 MB
    short* Wg       = (short*)(ws + (size_t)22 * 1024 * 1024);   // 49,152 B
    float* ctxtc    = (float*)(ws + (size_t)22 * 1024 * 1024 + 65536); // 64 KB

    // denom (1 MB) + counts (256 KB) contiguous: one memset
    hipMemsetAsync(denom, 0,
                   (size_t)NSEG * NH * sizeof(float) + (size_t)NSEG * sizeof(int),
                   stream);

    // fused prep: count histogram + Wg + ctxtc
    k_misc<<<4096 + 96 + 64, 256, 0, stream>>>(W1, b1, globs, cndts,
                                               batch_idx, recv_idx,
                                               Wg, ctxtc, counts);
    k_scan1<<<NSEG / 256, 256, 0, stream>>>(counts, tmp_excl, bsums);
    k_scan3<<<NSEG / 256, 256, 0, stream>>>(tmp_excl, bsums, offs, cursor);

    // MLP (+ fused scatter)
    k_mlp_mfma<<<GRIDM, 512, 0, stream>>>(pooled, edges, Wg, ctxtc, W2,
                                          batch_idx, recv_idx, ex, denom,
                                          cursor, elist);

    // final weighted pool
    k_gather<<<(NSEG * 64) / 256, 256, 0, stream>>>(new_edges, ex, denom,
                                                    offs, counts, elist, out);
}